// Round 12
// baseline (422.499 us; speedup 1.0000x reference)
//
#include <hip/hip_runtime.h>

#define NROWS 8192
#define BBND  32
#define CBND  512
#define JQ    4096            // j-range per block (2 halves)
#define NR    64              // rounds of 64j per block
#define ABUFB 4096            // A LDS buffer bytes (32 rows x 128B)

typedef unsigned short u16;
typedef unsigned int   u32;
typedef __bf16 bf16x8 __attribute__((ext_vector_type(8)));
typedef float  f32x4  __attribute__((ext_vector_type(4)));
typedef float  f32x16 __attribute__((ext_vector_type(16)));
typedef u32    u32x4  __attribute__((ext_vector_type(4)));
typedef u32    u32x2  __attribute__((ext_vector_type(2)));

#define ZERO4  (f32x4){0.f,0.f,0.f,0.f}
#define ZERO16 (f32x16){0.f,0.f,0.f,0.f,0.f,0.f,0.f,0.f,0.f,0.f,0.f,0.f,0.f,0.f,0.f,0.f}

// raw barrier: drain LDS ops, keep global loads in flight (no vmcnt drain)
#define BAR asm volatile("s_waitcnt lgkmcnt(0)\n\ts_barrier" ::: "memory")

static __device__ inline u16 f2bf(float f) {
    unsigned u = __builtin_bit_cast(unsigned, f);
    unsigned r = (u + 0x7FFFu + ((u >> 16) & 1u)) >> 16;
    return (u16)r;
}

static __device__ inline float pow14(float base) {
    return __builtin_amdgcn_exp2f(1.4f * __builtin_amdgcn_logf(base));
}

static __device__ inline float adj_eval(float dot, float sij) {
    float x = fabsf(2.f * dot - sij);
    float base = fmaxf(1.f - x * (1.f / 32.f), 0.f);
    return pow14(base);
}

static __device__ inline float sigmoidf_fast(float v) {
    float e = __builtin_amdgcn_exp2f(-1.44269504f * v);
    return 1.f / (1.f + e);
}

static __device__ inline u32 cvtpk(float a, float b) {
    u32 r;
    asm("v_cvt_pk_bf16_f32 %0, %1, %2" : "=v"(r) : "v"(a), "v"(b));
    return r;
}

static __device__ inline f32x4 MFMA16(bf16x8 a, bf16x8 b, f32x4 c) {
    return __builtin_amdgcn_mfma_f32_16x16x32_bf16(a, b, c, 0, 0, 0);
}
static __device__ inline f32x16 MFMA32(bf16x8 a, bf16x8 b, f32x16 c) {
    return __builtin_amdgcn_mfma_f32_32x32x16_bf16(a, b, c, 0, 0, 0);
}

// ---------------- prep: row sums of bbn + bf16 copy ----------------
__global__ __launch_bounds__(256) void k_prep_rows(const float* __restrict__ bbn,
                                                   float* __restrict__ s,
                                                   u16* __restrict__ bbn_bf) {
    int i = blockIdx.x * 256 + threadIdx.x;
    if (i >= NROWS) return;
    const f32x4* row = reinterpret_cast<const f32x4*>(bbn + i * BBND);
    float sum = 0.f;
    u16* dst = bbn_bf + i * BBND;
#pragma unroll
    for (int q = 0; q < 8; ++q) {
        f32x4 v = row[q];
#pragma unroll
        for (int e = 0; e < 4; ++e) {
            sum += v[e];
            dst[q * 4 + e] = f2bf(v[e]);
        }
    }
    s[i] = sum;
}

// ---------------- prep: W transpose -> bf16 ----------------
__global__ __launch_bounds__(256) void k_prep_wt(const float* __restrict__ W,
                                                 u16* __restrict__ WT) {
    int idx = blockIdx.x * 256 + threadIdx.x;   // over 512*512
    int c = idx >> 9, k = idx & 511;
    WT[idx] = f2bf(W[k * CBND + c]);            // WT[c][k]
}

// ---------------- degree: d_i = sum_j adj_ij ; dinv = rsqrt(d+eps) ----------------
__global__ __launch_bounds__(512) void k_deg(const u16* __restrict__ bbn_bf,
                                             const float* __restrict__ s,
                                             float* __restrict__ dinv) {
    __shared__ float part[8][16];
    int ibase = blockIdx.x * 16;
    int tid = threadIdx.x;
    int w = tid >> 6, l = tid & 63, lg = l >> 4, lr = l & 15;

    bf16x8 afrag = *reinterpret_cast<const bf16x8*>(bbn_bf + (ibase + lr) * BBND + lg * 8);
    float si[4];
#pragma unroll
    for (int r = 0; r < 4; ++r) si[r] = s[ibase + lg * 4 + r];

    float dacc[4] = {0.f, 0.f, 0.f, 0.f};
    int j0 = w * (NROWS / 8);
    for (int jt = 0; jt < NROWS / 8; jt += 16) {
        int jb = j0 + jt;
        bf16x8 bfrag = *reinterpret_cast<const bf16x8*>(bbn_bf + (jb + lr) * BBND + lg * 8);
        f32x4 dot = MFMA16(afrag, bfrag, ZERO4);
        float sj = s[jb + lr];
#pragma unroll
        for (int r = 0; r < 4; ++r) dacc[r] += adj_eval(dot[r], si[r] + sj);
    }
#pragma unroll
    for (int off = 1; off < 16; off <<= 1)
#pragma unroll
        for (int r = 0; r < 4; ++r) dacc[r] += __shfl_xor(dacc[r], off, 64);

    if (lr == 0) {
#pragma unroll
        for (int r = 0; r < 4; ++r) part[w][lg * 4 + r] = dacc[r];
    }
    __syncthreads();
    if (tid < 16) {
        float d = 0.f;
#pragma unroll
        for (int q = 0; q < 8; ++q) d += part[q][tid];
        dinv[ibase + tid] = rsqrtf(d + 1e-8f);
    }
}

// ---------------- fc: g_blk[(j>>3)*512 + c][j&7] = dinv_j * (cbn@W + b)[j][c] ----------------
// bid remap (cb = bx>>7): the 128 blocks sharing a cb are consecutive ->
// each XCD re-reads its own cbn slice from its L2 across all 8 cb phases.
__global__ __launch_bounds__(256) void k_fc(const float* __restrict__ cbn,
                                            const u16* __restrict__ WT,
                                            const float* __restrict__ bvec,
                                            const float* __restrict__ dinv,
                                            u16* __restrict__ g_blk) {
    int bid = blockIdx.x;
    int cb = bid >> 7, jb = bid & 127;
    int tid = threadIdx.x, w = tid >> 6, l = tid & 63, lg = l >> 4, lr = l & 15;
    int crow = cb * 64 + w * 16;
    int jcol = jb * 64;

    f32x4 acc[4];
#pragma unroll
    for (int f = 0; f < 4; ++f) acc[f] = ZERO4;

    for (int k0 = 0; k0 < CBND; k0 += 32) {
        bf16x8 afrag = *reinterpret_cast<const bf16x8*>(WT + (crow + lr) * CBND + k0 + lg * 8);
#pragma unroll
        for (int f = 0; f < 4; ++f) {
            const float* src = cbn + (jcol + f * 16 + lr) * CBND + k0 + lg * 8;
            f32x4 v0 = *reinterpret_cast<const f32x4*>(src);
            f32x4 v1 = *reinterpret_cast<const f32x4*>(src + 4);
            bf16x8 bfrag;
#pragma unroll
            for (int e = 0; e < 4; ++e) { bfrag[e] = (__bf16)v0[e]; bfrag[e + 4] = (__bf16)v1[e]; }
            acc[f] = MFMA16(afrag, bfrag, acc[f]);
        }
    }
#pragma unroll
    for (int f = 0; f < 4; ++f) {
#pragma unroll
        for (int r = 0; r < 4; ++r) {
            int c = crow + lg * 4 + r;
            int j = jcol + f * 16 + lr;
            float val = acc[f][r] + bvec[c];
            g_blk[(((j >> 3) * 512 + c) << 3) + (j & 7)] = f2bf(val * dinv[j]);
        }
    }
}

// ---------------- conv: partial sums P[jh] = sum_{j in half} adj_ij * g[:,j] ----------------
// Grid 512 = 256 i-tiles x 2 j-halves; block 512 thr (8 waves), tile 32i x 512c.
// __launch_bounds__(512,8) -> 4 blocks/CU, 32 waves/CU (2x round-11 TLP).
// Wave roles: acc wave w owns c = w*64..+64 (NO duplication); gen quad grid
// iq = w&1 (2 x 16i), jq8 = w>>1 (4 x 16j). All per-lane formulas (A swizzle
// phys slot = logical ^ (row&7), g_blk octet addressing, MFMA k-order) are
// round-11-verbatim -> accumulation chains bit-identical (absmax 0.00390625).
// jq = bx&1 constant per XCD (stride-8 dispatch) -> 4MB g j-slice L2-resident.

#define LOADB(T, R) { \
    const char* p = gB + (long)(T) * 32768; \
    R##0 = *reinterpret_cast<const u32x4*>(p); \
    R##1 = *reinterpret_cast<const u32x4*>(p + 512); \
    R##2 = *reinterpret_cast<const u32x4*>(p + 16384); \
    R##3 = *reinterpret_cast<const u32x4*>(p + 16384 + 512); \
}

#define GEN(ST, WB) { \
    int jg = jbase + (ST) * 64 + jq8 * 16; \
    bf16x8 fJ = *reinterpret_cast<const bf16x8*>(bbn_bf + (jg + lr) * BBND + lg * 8); \
    f32x4 sj = *reinterpret_cast<const f32x4*>(s + jg + lg * 4); \
    f32x4 dot = MFMA16(fJ, fragI, ZERO4); \
    u32 p0 = cvtpk(adj_eval(dot[0], si + sj[0]), adj_eval(dot[1], si + sj[1])); \
    u32 p1 = cvtpk(adj_eval(dot[2], si + sj[2]), adj_eval(dot[3], si + sj[3])); \
    *reinterpret_cast<u32x2*>(Ab + (WB) * ABUFB + gw) = (u32x2){p0, p1}; \
}

#define CONVP(RB, AK0, AK1, R) { \
    const char* Ar = Ab + (RB) * ABUFB; \
    bf16x8 ak0 = *reinterpret_cast<const bf16x8*>(Ar + (AK0)); \
    bf16x8 ak1 = *reinterpret_cast<const bf16x8*>(Ar + (AK1)); \
    acc0 = MFMA32(ak0, __builtin_bit_cast(bf16x8, R##0), acc0); \
    acc1 = MFMA32(ak0, __builtin_bit_cast(bf16x8, R##1), acc1); \
    acc0 = MFMA32(ak1, __builtin_bit_cast(bf16x8, R##2), acc0); \
    acc1 = MFMA32(ak1, __builtin_bit_cast(bf16x8, R##3), acc1); \
}

#define EPI(ACC, CT) { \
    _Pragma("unroll") \
    for (int reg = 0; reg < 16; ++reg) { \
        int rowD = (reg & 3) + 8 * (reg >> 2) + 4 * lh; \
        Pq[(long)(ibase + rowD) * CBND + w * 64 + (CT) * 32 + l31] = ACC[reg]; \
    } \
}

__global__ __launch_bounds__(512, 8) void k_conv(const u16* __restrict__ bbn_bf,
                                                 const float* __restrict__ s,
                                                 const u16* __restrict__ g_blk,
                                                 float* __restrict__ P) {
    __shared__ __align__(16) u16 Alds[2][32 * 64];   // 2 x 4KB supertiles

    int bx = blockIdx.x;
    int jq = bx & 1;                   // j-half; constant per XCD (stride-8 dispatch)
    int it = bx >> 1;                  // 0..255
    int ibase = it * 32;
    int jbase = jq * JQ;

    int tid = threadIdx.x;
    int w = tid >> 6, l = tid & 63;
    int lr = l & 15, lg = l >> 4, l31 = l & 31, lh = l >> 5;
    int iq = w & 1, jq8 = w >> 1;      // gen wave tile: 16i x 16j (2x4 waves)

    // gen hoists
    bf16x8 fragI = *reinterpret_cast<const bf16x8*>(bbn_bf + (ibase + iq * 16 + lr) * BBND + lg * 8);
    float si = s[ibase + iq * 16 + lr];

    char* Ab = (char*)&Alds[0][0];
    float* Pq = P + (long)jq * (NROWS * CBND);

    // B global base: octet (jbase/8 + T*4 + kc*2 + lh), c = w*64 (+ct*32) + l31
    const char* gB = (const char*)g_blk + (long)jbase * 1024 + lh * 8192
                   + (w * 64 + l31) * 16;

    // A-frag reads: row = l31 (128B rows), slot = tpar*4 + kc*2 + lh,
    // phys = slot ^ (row&7)
    int r7 = l31 & 7;
    int abase = l31 * 128;
    int a00 = abase + (((0 + lh) ^ r7) << 4);   // tpar0 kc0
    int a01 = abase + (((2 + lh) ^ r7) << 4);   // tpar0 kc1
    int a10 = abase + (((4 + lh) ^ r7) << 4);   // tpar1 kc0
    int a11 = abase + (((6 + lh) ^ r7) << 4);   // tpar1 kc1

    // gen write: row = iq*16+lr, logical slot = jq8*2 + (lg>>1), byte +(lg&1)*8
    int grow = iq * 16 + lr;
    int gw = grow * 128 + (((jq8 * 2 + (lg >> 1)) ^ (grow & 7)) << 4) + (lg & 1) * 8;

    f32x16 acc0 = ZERO16, acc1 = ZERO16;

    u32x4 rA0, rA1, rA2, rA3;
    u32x4 rB0, rB1, rB2, rB3;

    // prologue: supertile 0 into buf0, B(t=0) into rA
    GEN(0, 0);
    LOADB(0, rA);
    BAR;

    for (int st = 0; st < NR; ++st) {
        int rb = st & 1, wb = rb ^ 1;
        LOADB(2 * st + 1, rB);
        if (st + 1 < NR) GEN(st + 1, wb);
        CONVP(rb, a00, a01, rA);
        int tn = (2 * st + 2 < 2 * NR) ? 2 * st + 2 : 2 * NR - 1;  // tail: redundant
        LOADB(tn, rA);
        CONVP(rb, a10, a11, rB);
        BAR;
    }

    EPI(acc0, 0);
    EPI(acc1, 1);
}

// ---------------- combine: out = sigmoid(dinv_i * (P0 + P1)) ----------------
__global__ __launch_bounds__(256) void k_comb(const float* __restrict__ dinv,
                                              const float* __restrict__ P,
                                              float* __restrict__ out) {
    int idx = blockIdx.x * 256 + threadIdx.x;   // f32x4 index; 1,048,576 total
    float di = dinv[idx >> 7];
    f32x4 a = *reinterpret_cast<const f32x4*>(P + (long)idx * 4);
    f32x4 b = *reinterpret_cast<const f32x4*>(P + (long)NROWS * CBND + (long)idx * 4);
    f32x4 v;
#pragma unroll
    for (int e = 0; e < 4; ++e) v[e] = sigmoidf_fast((a[e] + b[e]) * di);
    *reinterpret_cast<f32x4*>(out + (long)idx * 4) = v;
}

extern "C" void kernel_launch(void* const* d_in, const int* in_sizes, int n_in,
                              void* d_out, int out_size, void* d_ws, size_t ws_size,
                              hipStream_t stream) {
    const float* bbn = (const float*)d_in[0];   // [8192,32]
    const float* cbn = (const float*)d_in[1];   // [8192,512]
    const float* W   = (const float*)d_in[2];   // [512,512]
    const float* b   = (const float*)d_in[3];   // [512]
    float* out = (float*)d_out;                 // [8192,512] f32

    char* ws = (char*)d_ws;
    float* s      = (float*)ws;  ws += NROWS * 4;
    float* dinv   = (float*)ws;  ws += NROWS * 4;
    u16* bbn_bf   = (u16*)ws;    ws += NROWS * BBND * 2;
    u16* WT       = (u16*)ws;    ws += CBND * CBND * 2;
    u16* g_blk    = (u16*)ws;    ws += (size_t)CBND * NROWS * 2;
    float* P      = (float*)ws;  ws += (size_t)2 * NROWS * CBND * 4;   // 32MB partials

    k_prep_rows<<<NROWS / 256, 256, 0, stream>>>(bbn, s, bbn_bf);
    k_prep_wt<<<(CBND * CBND) / 256, 256, 0, stream>>>(W, WT);
    k_deg<<<NROWS / 16, 512, 0, stream>>>(bbn_bf, s, dinv);
    k_fc<<<(NROWS / 64) * (CBND / 64), 256, 0, stream>>>(cbn, WT, b, dinv, g_blk);
    k_conv<<<(NROWS / 32) * 2, 512, 0, stream>>>(bbn_bf, s, g_blk, P);
    k_comb<<<(NROWS * CBND / 4) / 256, 256, 0, stream>>>(dinv, P, out);
}

// Round 13
// 255.339 us; speedup vs baseline: 1.6547x; 1.6547x over previous
//
#include <hip/hip_runtime.h>

#define NROWS 8192
#define BBND  32
#define CBND  512
#define JQ    4096            // j-range per block (2 halves)
#define NR    64              // rounds of 64j per block
#define ABUFB 4096            // A LDS buffer bytes (32 rows x 128B)

typedef unsigned short u16;
typedef unsigned int   u32;
typedef __bf16 bf16x8 __attribute__((ext_vector_type(8)));
typedef float  f32x4  __attribute__((ext_vector_type(4)));
typedef float  f32x16 __attribute__((ext_vector_type(16)));
typedef u32    u32x4  __attribute__((ext_vector_type(4)));
typedef u32    u32x2  __attribute__((ext_vector_type(2)));

#define ZERO4  (f32x4){0.f,0.f,0.f,0.f}
#define ZERO16 (f32x16){0.f,0.f,0.f,0.f,0.f,0.f,0.f,0.f,0.f,0.f,0.f,0.f,0.f,0.f,0.f,0.f}

// raw barrier: drain LDS ops, keep global loads in flight (no vmcnt drain)
#define BAR asm volatile("s_waitcnt lgkmcnt(0)\n\ts_barrier" ::: "memory")

static __device__ inline u16 f2bf(float f) {
    unsigned u = __builtin_bit_cast(unsigned, f);
    unsigned r = (u + 0x7FFFu + ((u >> 16) & 1u)) >> 16;
    return (u16)r;
}

static __device__ inline float pow14(float base) {
    return __builtin_amdgcn_exp2f(1.4f * __builtin_amdgcn_logf(base));
}

static __device__ inline float adj_eval(float dot, float sij) {
    float x = fabsf(2.f * dot - sij);
    float base = fmaxf(1.f - x * (1.f / 32.f), 0.f);
    return pow14(base);
}

static __device__ inline float sigmoidf_fast(float v) {
    float e = __builtin_amdgcn_exp2f(-1.44269504f * v);
    return 1.f / (1.f + e);
}

static __device__ inline u32 cvtpk(float a, float b) {
    u32 r;
    asm("v_cvt_pk_bf16_f32 %0, %1, %2" : "=v"(r) : "v"(a), "v"(b));
    return r;
}

static __device__ inline f32x4 MFMA16(bf16x8 a, bf16x8 b, f32x4 c) {
    return __builtin_amdgcn_mfma_f32_16x16x32_bf16(a, b, c, 0, 0, 0);
}
static __device__ inline f32x16 MFMA32(bf16x8 a, bf16x8 b, f32x16 c) {
    return __builtin_amdgcn_mfma_f32_32x32x16_bf16(a, b, c, 0, 0, 0);
}

// ---------------- prep: row sums of bbn + bf16 copy ----------------
__global__ __launch_bounds__(256) void k_prep_rows(const float* __restrict__ bbn,
                                                   float* __restrict__ s,
                                                   u16* __restrict__ bbn_bf) {
    int i = blockIdx.x * 256 + threadIdx.x;
    if (i >= NROWS) return;
    const f32x4* row = reinterpret_cast<const f32x4*>(bbn + i * BBND);
    float sum = 0.f;
    u16* dst = bbn_bf + i * BBND;
#pragma unroll
    for (int q = 0; q < 8; ++q) {
        f32x4 v = row[q];
#pragma unroll
        for (int e = 0; e < 4; ++e) {
            sum += v[e];
            dst[q * 4 + e] = f2bf(v[e]);
        }
    }
    s[i] = sum;
}

// ---------------- prep: W transpose -> bf16 ----------------
__global__ __launch_bounds__(256) void k_prep_wt(const float* __restrict__ W,
                                                 u16* __restrict__ WT) {
    int idx = blockIdx.x * 256 + threadIdx.x;   // over 512*512
    int c = idx >> 9, k = idx & 511;
    WT[idx] = f2bf(W[k * CBND + c]);            // WT[c][k]
}

// ---------------- degree: d_i = sum_j adj_ij ; dinv = rsqrt(d+eps) ----------------
__global__ __launch_bounds__(512) void k_deg(const u16* __restrict__ bbn_bf,
                                             const float* __restrict__ s,
                                             float* __restrict__ dinv) {
    __shared__ float part[8][16];
    int ibase = blockIdx.x * 16;
    int tid = threadIdx.x;
    int w = tid >> 6, l = tid & 63, lg = l >> 4, lr = l & 15;

    bf16x8 afrag = *reinterpret_cast<const bf16x8*>(bbn_bf + (ibase + lr) * BBND + lg * 8);
    float si[4];
#pragma unroll
    for (int r = 0; r < 4; ++r) si[r] = s[ibase + lg * 4 + r];

    float dacc[4] = {0.f, 0.f, 0.f, 0.f};
    int j0 = w * (NROWS / 8);
    for (int jt = 0; jt < NROWS / 8; jt += 16) {
        int jb = j0 + jt;
        bf16x8 bfrag = *reinterpret_cast<const bf16x8*>(bbn_bf + (jb + lr) * BBND + lg * 8);
        f32x4 dot = MFMA16(afrag, bfrag, ZERO4);
        float sj = s[jb + lr];
#pragma unroll
        for (int r = 0; r < 4; ++r) dacc[r] += adj_eval(dot[r], si[r] + sj);
    }
#pragma unroll
    for (int off = 1; off < 16; off <<= 1)
#pragma unroll
        for (int r = 0; r < 4; ++r) dacc[r] += __shfl_xor(dacc[r], off, 64);

    if (lr == 0) {
#pragma unroll
        for (int r = 0; r < 4; ++r) part[w][lg * 4 + r] = dacc[r];
    }
    __syncthreads();
    if (tid < 16) {
        float d = 0.f;
#pragma unroll
        for (int q = 0; q < 8; ++q) d += part[q][tid];
        dinv[ibase + tid] = rsqrtf(d + 1e-8f);
    }
}

// ---------------- fc: g_blk[(j>>3)*512 + c][j&7] = dinv_j * (cbn@W + b)[j][c] ----------------
// bid remap (cb = bx>>7): the 128 blocks sharing a cb are consecutive ->
// each XCD re-reads its own cbn slice from its L2 across all 8 cb phases.
__global__ __launch_bounds__(256) void k_fc(const float* __restrict__ cbn,
                                            const u16* __restrict__ WT,
                                            const float* __restrict__ bvec,
                                            const float* __restrict__ dinv,
                                            u16* __restrict__ g_blk) {
    int bid = blockIdx.x;
    int cb = bid >> 7, jb = bid & 127;
    int tid = threadIdx.x, w = tid >> 6, l = tid & 63, lg = l >> 4, lr = l & 15;
    int crow = cb * 64 + w * 16;
    int jcol = jb * 64;

    f32x4 acc[4];
#pragma unroll
    for (int f = 0; f < 4; ++f) acc[f] = ZERO4;

    for (int k0 = 0; k0 < CBND; k0 += 32) {
        bf16x8 afrag = *reinterpret_cast<const bf16x8*>(WT + (crow + lr) * CBND + k0 + lg * 8);
#pragma unroll
        for (int f = 0; f < 4; ++f) {
            const float* src = cbn + (jcol + f * 16 + lr) * CBND + k0 + lg * 8;
            f32x4 v0 = *reinterpret_cast<const f32x4*>(src);
            f32x4 v1 = *reinterpret_cast<const f32x4*>(src + 4);
            bf16x8 bfrag;
#pragma unroll
            for (int e = 0; e < 4; ++e) { bfrag[e] = (__bf16)v0[e]; bfrag[e + 4] = (__bf16)v1[e]; }
            acc[f] = MFMA16(afrag, bfrag, acc[f]);
        }
    }
#pragma unroll
    for (int f = 0; f < 4; ++f) {
#pragma unroll
        for (int r = 0; r < 4; ++r) {
            int c = crow + lg * 4 + r;
            int j = jcol + f * 16 + lr;
            float val = acc[f][r] + bvec[c];
            g_blk[(((j >> 3) * 512 + c) << 3) + (j & 7)] = f2bf(val * dinv[j]);
        }
    }
}

// ---------------- conv: partial sums P[jh] = sum_{j in half} adj_ij * g[:,j] ----------------
// Round-12 structure (proven bit-identical, absmax 0.00390625) with the spill
// fixed: __launch_bounds__(512, 6) -> ~85 reg/wave budget >= ~80 demanded
// (32 AGPR acc + 32 VGPR rA/rB staging + addresses). 3 blocks/CU, 24 waves/CU.
// Round 12's (512,8) capped at 64 regs -> hot-loop scratch spill (420MB HBM
// writes, VGPR_Count 32). Everything below is round-12-verbatim.

#define LOADB(T, R) { \
    const char* p = gB + (long)(T) * 32768; \
    R##0 = *reinterpret_cast<const u32x4*>(p); \
    R##1 = *reinterpret_cast<const u32x4*>(p + 512); \
    R##2 = *reinterpret_cast<const u32x4*>(p + 16384); \
    R##3 = *reinterpret_cast<const u32x4*>(p + 16384 + 512); \
}

#define GEN(ST, WB) { \
    int jg = jbase + (ST) * 64 + jq8 * 16; \
    bf16x8 fJ = *reinterpret_cast<const bf16x8*>(bbn_bf + (jg + lr) * BBND + lg * 8); \
    f32x4 sj = *reinterpret_cast<const f32x4*>(s + jg + lg * 4); \
    f32x4 dot = MFMA16(fJ, fragI, ZERO4); \
    u32 p0 = cvtpk(adj_eval(dot[0], si + sj[0]), adj_eval(dot[1], si + sj[1])); \
    u32 p1 = cvtpk(adj_eval(dot[2], si + sj[2]), adj_eval(dot[3], si + sj[3])); \
    *reinterpret_cast<u32x2*>(Ab + (WB) * ABUFB + gw) = (u32x2){p0, p1}; \
}

#define CONVP(RB, AK0, AK1, R) { \
    const char* Ar = Ab + (RB) * ABUFB; \
    bf16x8 ak0 = *reinterpret_cast<const bf16x8*>(Ar + (AK0)); \
    bf16x8 ak1 = *reinterpret_cast<const bf16x8*>(Ar + (AK1)); \
    acc0 = MFMA32(ak0, __builtin_bit_cast(bf16x8, R##0), acc0); \
    acc1 = MFMA32(ak0, __builtin_bit_cast(bf16x8, R##1), acc1); \
    acc0 = MFMA32(ak1, __builtin_bit_cast(bf16x8, R##2), acc0); \
    acc1 = MFMA32(ak1, __builtin_bit_cast(bf16x8, R##3), acc1); \
}

#define EPI(ACC, CT) { \
    _Pragma("unroll") \
    for (int reg = 0; reg < 16; ++reg) { \
        int rowD = (reg & 3) + 8 * (reg >> 2) + 4 * lh; \
        Pq[(long)(ibase + rowD) * CBND + w * 64 + (CT) * 32 + l31] = ACC[reg]; \
    } \
}

__global__ __launch_bounds__(512, 6) void k_conv(const u16* __restrict__ bbn_bf,
                                                 const float* __restrict__ s,
                                                 const u16* __restrict__ g_blk,
                                                 float* __restrict__ P) {
    __shared__ __align__(16) u16 Alds[2][32 * 64];   // 2 x 4KB supertiles

    int bx = blockIdx.x;
    int jq = bx & 1;                   // j-half; constant per XCD (stride-8 dispatch)
    int it = bx >> 1;                  // 0..255
    int ibase = it * 32;
    int jbase = jq * JQ;

    int tid = threadIdx.x;
    int w = tid >> 6, l = tid & 63;
    int lr = l & 15, lg = l >> 4, l31 = l & 31, lh = l >> 5;
    int iq = w & 1, jq8 = w >> 1;      // gen wave tile: 16i x 16j (2x4 waves)

    // gen hoists
    bf16x8 fragI = *reinterpret_cast<const bf16x8*>(bbn_bf + (ibase + iq * 16 + lr) * BBND + lg * 8);
    float si = s[ibase + iq * 16 + lr];

    char* Ab = (char*)&Alds[0][0];
    float* Pq = P + (long)jq * (NROWS * CBND);

    // B global base: octet (jbase/8 + T*4 + kc*2 + lh), c = w*64 (+ct*32) + l31
    const char* gB = (const char*)g_blk + (long)jbase * 1024 + lh * 8192
                   + (w * 64 + l31) * 16;

    // A-frag reads: row = l31 (128B rows), slot = tpar*4 + kc*2 + lh,
    // phys = slot ^ (row&7)
    int r7 = l31 & 7;
    int abase = l31 * 128;
    int a00 = abase + (((0 + lh) ^ r7) << 4);   // tpar0 kc0
    int a01 = abase + (((2 + lh) ^ r7) << 4);   // tpar0 kc1
    int a10 = abase + (((4 + lh) ^ r7) << 4);   // tpar1 kc0
    int a11 = abase + (((6 + lh) ^ r7) << 4);   // tpar1 kc1

    // gen write: row = iq*16+lr, logical slot = jq8*2 + (lg>>1), byte +(lg&1)*8
    int grow = iq * 16 + lr;
    int gw = grow * 128 + (((jq8 * 2 + (lg >> 1)) ^ (grow & 7)) << 4) + (lg & 1) * 8;

    f32x16 acc0 = ZERO16, acc1 = ZERO16;

    u32x4 rA0, rA1, rA2, rA3;
    u32x4 rB0, rB1, rB2, rB3;

    // prologue: supertile 0 into buf0, B(t=0) into rA
    GEN(0, 0);
    LOADB(0, rA);
    BAR;

    for (int st = 0; st < NR; ++st) {
        int rb = st & 1, wb = rb ^ 1;
        LOADB(2 * st + 1, rB);
        if (st + 1 < NR) GEN(st + 1, wb);
        CONVP(rb, a00, a01, rA);
        int tn = (2 * st + 2 < 2 * NR) ? 2 * st + 2 : 2 * NR - 1;  // tail: redundant
        LOADB(tn, rA);
        CONVP(rb, a10, a11, rB);
        BAR;
    }

    EPI(acc0, 0);
    EPI(acc1, 1);
}

// ---------------- combine: out = sigmoid(dinv_i * (P0 + P1)) ----------------
__global__ __launch_bounds__(256) void k_comb(const float* __restrict__ dinv,
                                              const float* __restrict__ P,
                                              float* __restrict__ out) {
    int idx = blockIdx.x * 256 + threadIdx.x;   // f32x4 index; 1,048,576 total
    float di = dinv[idx >> 7];
    f32x4 a = *reinterpret_cast<const f32x4*>(P + (long)idx * 4);
    f32x4 b = *reinterpret_cast<const f32x4*>(P + (long)NROWS * CBND + (long)idx * 4);
    f32x4 v;
#pragma unroll
    for (int e = 0; e < 4; ++e) v[e] = sigmoidf_fast((a[e] + b[e]) * di);
    *reinterpret_cast<f32x4*>(out + (long)idx * 4) = v;
}

extern "C" void kernel_launch(void* const* d_in, const int* in_sizes, int n_in,
                              void* d_out, int out_size, void* d_ws, size_t ws_size,
                              hipStream_t stream) {
    const float* bbn = (const float*)d_in[0];   // [8192,32]
    const float* cbn = (const float*)d_in[1];   // [8192,512]
    const float* W   = (const float*)d_in[2];   // [512,512]
    const float* b   = (const float*)d_in[3];   // [512]
    float* out = (float*)d_out;                 // [8192,512] f32

    char* ws = (char*)d_ws;
    float* s      = (float*)ws;  ws += NROWS * 4;
    float* dinv   = (float*)ws;  ws += NROWS * 4;
    u16* bbn_bf   = (u16*)ws;    ws += NROWS * BBND * 2;
    u16* WT       = (u16*)ws;    ws += CBND * CBND * 2;
    u16* g_blk    = (u16*)ws;    ws += (size_t)CBND * NROWS * 2;
    float* P      = (float*)ws;  ws += (size_t)2 * NROWS * CBND * 4;   // 32MB partials

    k_prep_rows<<<NROWS / 256, 256, 0, stream>>>(bbn, s, bbn_bf);
    k_prep_wt<<<(CBND * CBND) / 256, 256, 0, stream>>>(W, WT);
    k_deg<<<NROWS / 16, 512, 0, stream>>>(bbn_bf, s, dinv);
    k_fc<<<(NROWS / 64) * (CBND / 64), 256, 0, stream>>>(cbn, WT, b, dinv, g_blk);
    k_conv<<<(NROWS / 32) * 2, 512, 0, stream>>>(bbn_bf, s, g_blk, P);
    k_comb<<<(NROWS * CBND / 4) / 256, 256, 0, stream>>>(dinv, P, out);
}

// Round 14
// 182.258 us; speedup vs baseline: 2.3181x; 1.4010x over previous
//
#include <hip/hip_runtime.h>

#define NROWS 8192
#define BBND  32
#define CBND  512
#define JQ    4096            // j-range per block (2 halves)
#define NR    64              // rounds of 64j per block
#define ABUFB 8192            // A LDS buffer bytes (64 rows x 128B)

typedef unsigned short u16;
typedef unsigned int   u32;
typedef __bf16 bf16x8 __attribute__((ext_vector_type(8)));
typedef float  f32x4  __attribute__((ext_vector_type(4)));
typedef float  f32x16 __attribute__((ext_vector_type(16)));
typedef u32    u32x4  __attribute__((ext_vector_type(4)));
typedef u32    u32x2  __attribute__((ext_vector_type(2)));

#define ZERO4  (f32x4){0.f,0.f,0.f,0.f}
#define ZERO16 (f32x16){0.f,0.f,0.f,0.f,0.f,0.f,0.f,0.f,0.f,0.f,0.f,0.f,0.f,0.f,0.f,0.f}

// raw barrier: drain LDS ops, keep global loads in flight (no vmcnt drain)
#define BAR asm volatile("s_waitcnt lgkmcnt(0)\n\ts_barrier" ::: "memory")

static __device__ inline u16 f2bf(float f) {
    unsigned u = __builtin_bit_cast(unsigned, f);
    unsigned r = (u + 0x7FFFu + ((u >> 16) & 1u)) >> 16;
    return (u16)r;
}

static __device__ inline float pow14(float base) {
    return __builtin_amdgcn_exp2f(1.4f * __builtin_amdgcn_logf(base));
}

static __device__ inline float adj_eval(float dot, float sij) {
    float x = fabsf(2.f * dot - sij);
    float base = fmaxf(1.f - x * (1.f / 32.f), 0.f);
    return pow14(base);
}

static __device__ inline float sigmoidf_fast(float v) {
    float e = __builtin_amdgcn_exp2f(-1.44269504f * v);
    return 1.f / (1.f + e);
}

static __device__ inline u32 cvtpk(float a, float b) {
    u32 r;
    asm("v_cvt_pk_bf16_f32 %0, %1, %2" : "=v"(r) : "v"(a), "v"(b));
    return r;
}

static __device__ inline f32x4 MFMA16(bf16x8 a, bf16x8 b, f32x4 c) {
    return __builtin_amdgcn_mfma_f32_16x16x32_bf16(a, b, c, 0, 0, 0);
}
static __device__ inline f32x16 MFMA32(bf16x8 a, bf16x8 b, f32x16 c) {
    return __builtin_amdgcn_mfma_f32_32x32x16_bf16(a, b, c, 0, 0, 0);
}

// ---------------- prep: row sums of bbn + bf16 copy ----------------
__global__ __launch_bounds__(256) void k_prep_rows(const float* __restrict__ bbn,
                                                   float* __restrict__ s,
                                                   u16* __restrict__ bbn_bf) {
    int i = blockIdx.x * 256 + threadIdx.x;
    if (i >= NROWS) return;
    const f32x4* row = reinterpret_cast<const f32x4*>(bbn + i * BBND);
    float sum = 0.f;
    u16* dst = bbn_bf + i * BBND;
#pragma unroll
    for (int q = 0; q < 8; ++q) {
        f32x4 v = row[q];
#pragma unroll
        for (int e = 0; e < 4; ++e) {
            sum += v[e];
            dst[q * 4 + e] = f2bf(v[e]);
        }
    }
    s[i] = sum;
}

// ---------------- prep: W transpose -> bf16 ----------------
__global__ __launch_bounds__(256) void k_prep_wt(const float* __restrict__ W,
                                                 u16* __restrict__ WT) {
    int idx = blockIdx.x * 256 + threadIdx.x;   // over 512*512
    int c = idx >> 9, k = idx & 511;
    WT[idx] = f2bf(W[k * CBND + c]);            // WT[c][k]
}

// ---------------- degree: d_i = sum_j adj_ij ; dinv = rsqrt(d+eps) ----------------
__global__ __launch_bounds__(512) void k_deg(const u16* __restrict__ bbn_bf,
                                             const float* __restrict__ s,
                                             float* __restrict__ dinv) {
    __shared__ float part[8][16];
    int ibase = blockIdx.x * 16;
    int tid = threadIdx.x;
    int w = tid >> 6, l = tid & 63, lg = l >> 4, lr = l & 15;

    bf16x8 afrag = *reinterpret_cast<const bf16x8*>(bbn_bf + (ibase + lr) * BBND + lg * 8);
    float si[4];
#pragma unroll
    for (int r = 0; r < 4; ++r) si[r] = s[ibase + lg * 4 + r];

    float dacc[4] = {0.f, 0.f, 0.f, 0.f};
    int j0 = w * (NROWS / 8);
    for (int jt = 0; jt < NROWS / 8; jt += 16) {
        int jb = j0 + jt;
        bf16x8 bfrag = *reinterpret_cast<const bf16x8*>(bbn_bf + (jb + lr) * BBND + lg * 8);
        f32x4 dot = MFMA16(afrag, bfrag, ZERO4);
        float sj = s[jb + lr];
#pragma unroll
        for (int r = 0; r < 4; ++r) dacc[r] += adj_eval(dot[r], si[r] + sj);
    }
#pragma unroll
    for (int off = 1; off < 16; off <<= 1)
#pragma unroll
        for (int r = 0; r < 4; ++r) dacc[r] += __shfl_xor(dacc[r], off, 64);

    if (lr == 0) {
#pragma unroll
        for (int r = 0; r < 4; ++r) part[w][lg * 4 + r] = dacc[r];
    }
    __syncthreads();
    if (tid < 16) {
        float d = 0.f;
#pragma unroll
        for (int q = 0; q < 8; ++q) d += part[q][tid];
        dinv[ibase + tid] = rsqrtf(d + 1e-8f);
    }
}

// ---------------- fc: g_blk[(j>>3)*512 + c][j&7] = dinv_j * (cbn@W + b)[j][c] ----------------
// LDS-staged: one block per 64-j tile (grid 128, 512 thr). The 64x512 cbn tile
// is converted to bf16 ONCE into LDS (64KB, slot^=row&7 swizzle) and consumed
// by all 8 c-quadrants -> cbn read from HBM exactly once (was 4-8x re-fetch,
// 66MB FETCH in r10). Same (__bf16) casts + same per-(c,j) MFMA K-chain as
// before -> g_blk bit-identical. Waves: wq = w&3 c-quarter, jh = w>>2 j-half.
__global__ __launch_bounds__(512) void k_fc(const float* __restrict__ cbn,
                                            const u16* __restrict__ WT,
                                            const float* __restrict__ bvec,
                                            const float* __restrict__ dinv,
                                            u16* __restrict__ g_blk) {
    __shared__ __align__(16) u16 Clds[64 * 512];   // 64 j-rows x 512 k (bf16)
    int jcol = blockIdx.x * 64;
    int tid = threadIdx.x;
    int w = tid >> 6, l = tid & 63, lg = l >> 4, lr = l & 15;
    int wq = w & 3, jh = w >> 2;

    char* Cl = (char*)&Clds[0];

    // stage: pass p, thread t covers 16B slot gidx = p*512+t of the 64x64-slot tile
#pragma unroll
    for (int p = 0; p < 8; ++p) {
        int gidx = p * 512 + tid;
        int row = gidx >> 6, sl = gidx & 63;
        const f32x4* src = reinterpret_cast<const f32x4*>(cbn + (jcol + row) * CBND + sl * 8);
        f32x4 v0 = src[0], v1 = src[1];
        bf16x8 bv;
#pragma unroll
        for (int e = 0; e < 4; ++e) { bv[e] = (__bf16)v0[e]; bv[e + 4] = (__bf16)v1[e]; }
        *reinterpret_cast<bf16x8*>(Cl + row * 1024 + ((sl ^ (row & 7)) << 4)) = bv;
    }
    __syncthreads();

    int r7 = lr & 7;
    for (int cb = 0; cb < 8; ++cb) {
        int crow = cb * 64 + wq * 16;
        f32x4 acc0 = ZERO4, acc1 = ZERO4;
        for (int k0 = 0; k0 < CBND; k0 += 32) {
            bf16x8 afrag = *reinterpret_cast<const bf16x8*>(WT + (crow + lr) * CBND + k0 + lg * 8);
            int slot = (k0 >> 3) + lg;
            int row0 = jh * 32 + lr;
            bf16x8 b0 = *reinterpret_cast<const bf16x8*>(Cl + row0 * 1024 + ((slot ^ r7) << 4));
            bf16x8 b1 = *reinterpret_cast<const bf16x8*>(Cl + (row0 + 16) * 1024 + ((slot ^ r7) << 4));
            acc0 = MFMA16(afrag, b0, acc0);
            acc1 = MFMA16(afrag, b1, acc1);
        }
#pragma unroll
        for (int f = 0; f < 2; ++f) {
            f32x4 af = f ? acc1 : acc0;
#pragma unroll
            for (int r = 0; r < 4; ++r) {
                int c = crow + lg * 4 + r;
                int j = jcol + jh * 32 + f * 16 + lr;
                float val = af[r] + bvec[c];
                g_blk[(((j >> 3) * 512 + c) << 3) + (j & 7)] = f2bf(val * dinv[j]);
            }
        }
    }
}

// ---------------- conv: partial sums P[jh] = sum_{j in half} adj_ij * g[:,j] ----------------
// ROUND-11 VERBATIM (best measured: 116.9us, absmax 0.00390625).
// Grid 256 = 128 i-tiles x 2 j-halves (1 block/CU, 16 waves). Block 1024 thr,
// tile 64i x 512c, JQ=4096 (64 rounds of 64j). adj generated exactly ONCE per
// (i,j). No atomics: plain stores to P[jh]. jq = bx&1 constant per XCD.

#define LOADB(T, R) { \
    const char* p = gB + (long)(T) * 32768; \
    R##0 = *reinterpret_cast<const u32x4*>(p); \
    R##1 = *reinterpret_cast<const u32x4*>(p + 512); \
    R##2 = *reinterpret_cast<const u32x4*>(p + 16384); \
    R##3 = *reinterpret_cast<const u32x4*>(p + 16384 + 512); \
}

#define GEN(ST, WB) { \
    int jg = jbase + (ST) * 64 + jq8 * 16; \
    bf16x8 fJ = *reinterpret_cast<const bf16x8*>(bbn_bf + (jg + lr) * BBND + lg * 8); \
    f32x4 sj = *reinterpret_cast<const f32x4*>(s + jg + lg * 4); \
    f32x4 dot = MFMA16(fJ, fragI, ZERO4); \
    u32 p0 = cvtpk(adj_eval(dot[0], si + sj[0]), adj_eval(dot[1], si + sj[1])); \
    u32 p1 = cvtpk(adj_eval(dot[2], si + sj[2]), adj_eval(dot[3], si + sj[3])); \
    *reinterpret_cast<u32x2*>(Ab + (WB) * ABUFB + gw) = (u32x2){p0, p1}; \
}

#define CONVP(RB, AK0, AK1, R) { \
    const char* Ar = Ab + (RB) * ABUFB; \
    bf16x8 ak0 = *reinterpret_cast<const bf16x8*>(Ar + (AK0)); \
    bf16x8 ak1 = *reinterpret_cast<const bf16x8*>(Ar + (AK1)); \
    acc0 = MFMA32(ak0, __builtin_bit_cast(bf16x8, R##0), acc0); \
    acc1 = MFMA32(ak0, __builtin_bit_cast(bf16x8, R##1), acc1); \
    acc0 = MFMA32(ak1, __builtin_bit_cast(bf16x8, R##2), acc0); \
    acc1 = MFMA32(ak1, __builtin_bit_cast(bf16x8, R##3), acc1); \
}

#define EPI(ACC, CT) { \
    _Pragma("unroll") \
    for (int reg = 0; reg < 16; ++reg) { \
        int rowD = (reg & 3) + 8 * (reg >> 2) + 4 * lh; \
        Pq[(long)(ibase + iw * 32 + rowD) * CBND + cw * 64 + (CT) * 32 + l31] = ACC[reg]; \
    } \
}

__global__ __launch_bounds__(1024, 4) void k_conv(const u16* __restrict__ bbn_bf,
                                                  const float* __restrict__ s,
                                                  const u16* __restrict__ g_blk,
                                                  float* __restrict__ P) {
    __shared__ __align__(16) u16 Alds[2][64 * 64];   // 2 x 8KB supertiles

    int bx = blockIdx.x;
    int jq = bx & 1;                   // j-half; constant per XCD (stride-8 dispatch)
    int it = bx >> 1;                  // 0..127
    int ibase = it * 64;
    int jbase = jq * JQ;

    int tid = threadIdx.x;
    int w = tid >> 6, l = tid & 63;
    int lr = l & 15, lg = l >> 4, l31 = l & 31, lh = l >> 5;
    int iw = w & 1, cw = w >> 1;       // acc wave tile: 32i x 64c (2x8 waves)
    int iq = w & 3, jq8 = w >> 2;      // gen wave tile: 16i x 16j (4x4 waves)

    // gen hoists
    bf16x8 fragI = *reinterpret_cast<const bf16x8*>(bbn_bf + (ibase + iq * 16 + lr) * BBND + lg * 8);
    float si = s[ibase + iq * 16 + lr];

    char* Ab = (char*)&Alds[0][0];
    float* Pq = P + (long)jq * (NROWS * CBND);

    // B global base: octet (jbase/8 + T*4 + kc*2 + lh), c = cw*64 (+ct*32) + l31
    const char* gB = (const char*)g_blk + (long)jbase * 1024 + lh * 8192
                   + (cw * 64 + l31) * 16;

    // A-frag reads: row = iw*32 + l31 (128B rows), slot = tpar*4 + kc*2 + lh,
    // phys = slot ^ (row&7)
    int arow = iw * 32 + l31;
    int r7 = arow & 7;
    int abase = arow * 128;
    int a00 = abase + (((0 + lh) ^ r7) << 4);   // tpar0 kc0
    int a01 = abase + (((2 + lh) ^ r7) << 4);   // tpar0 kc1
    int a10 = abase + (((4 + lh) ^ r7) << 4);   // tpar1 kc0
    int a11 = abase + (((6 + lh) ^ r7) << 4);   // tpar1 kc1

    // gen write: row = iq*16+lr, logical slot = jq8*2 + (lg>>1), byte +(lg&1)*8
    int grow = iq * 16 + lr;
    int gw = grow * 128 + (((jq8 * 2 + (lg >> 1)) ^ (grow & 7)) << 4) + (lg & 1) * 8;

    f32x16 acc0 = ZERO16, acc1 = ZERO16;

    u32x4 rA0, rA1, rA2, rA3;
    u32x4 rB0, rB1, rB2, rB3;

    // prologue: supertile 0 into buf0, B(t=0) into rA
    GEN(0, 0);
    LOADB(0, rA);
    BAR;

    for (int st = 0; st < NR; ++st) {
        int rb = st & 1, wb = rb ^ 1;
        LOADB(2 * st + 1, rB);
        if (st + 1 < NR) GEN(st + 1, wb);
        CONVP(rb, a00, a01, rA);
        int tn = (2 * st + 2 < 2 * NR) ? 2 * st + 2 : 2 * NR - 1;  // tail: redundant
        LOADB(tn, rA);
        CONVP(rb, a10, a11, rB);
        BAR;
    }

    EPI(acc0, 0);
    EPI(acc1, 1);
}

// ---------------- combine: out = sigmoid(dinv_i * (P0 + P1)) ----------------
__global__ __launch_bounds__(256) void k_comb(const float* __restrict__ dinv,
                                              const float* __restrict__ P,
                                              float* __restrict__ out) {
    int idx = blockIdx.x * 256 + threadIdx.x;   // f32x4 index; 1,048,576 total
    float di = dinv[idx >> 7];
    f32x4 a = *reinterpret_cast<const f32x4*>(P + (long)idx * 4);
    f32x4 b = *reinterpret_cast<const f32x4*>(P + (long)NROWS * CBND + (long)idx * 4);
    f32x4 v;
#pragma unroll
    for (int e = 0; e < 4; ++e) v[e] = sigmoidf_fast((a[e] + b[e]) * di);
    *reinterpret_cast<f32x4*>(out + (long)idx * 4) = v;
}

extern "C" void kernel_launch(void* const* d_in, const int* in_sizes, int n_in,
                              void* d_out, int out_size, void* d_ws, size_t ws_size,
                              hipStream_t stream) {
    const float* bbn = (const float*)d_in[0];   // [8192,32]
    const float* cbn = (const float*)d_in[1];   // [8192,512]
    const float* W   = (const float*)d_in[2];   // [512,512]
    const float* b   = (const float*)d_in[3];   // [512]
    float* out = (float*)d_out;                 // [8192,512] f32

    char* ws = (char*)d_ws;
    float* s      = (float*)ws;  ws += NROWS * 4;
    float* dinv   = (float*)ws;  ws += NROWS * 4;
    u16* bbn_bf   = (u16*)ws;    ws += NROWS * BBND * 2;
    u16* WT       = (u16*)ws;    ws += CBND * CBND * 2;
    u16* g_blk    = (u16*)ws;    ws += (size_t)CBND * NROWS * 2;
    float* P      = (float*)ws;  ws += (size_t)2 * NROWS * CBND * 4;   // 32MB partials

    k_prep_rows<<<NROWS / 256, 256, 0, stream>>>(bbn, s, bbn_bf);
    k_prep_wt<<<(CBND * CBND) / 256, 256, 0, stream>>>(W, WT);
    k_deg<<<NROWS / 16, 512, 0, stream>>>(bbn_bf, s, dinv);
    k_fc<<<NROWS / 64, 512, 0, stream>>>(cbn, WT, b, dinv, g_blk);
    k_conv<<<(NROWS / 64) * 2, 1024, 0, stream>>>(bbn_bf, s, g_blk, P);
    k_comb<<<(NROWS * CBND / 4) / 256, 256, 0, stream>>>(dinv, P, out);
}

// Round 15
// 162.283 us; speedup vs baseline: 2.6035x; 1.1231x over previous
//
#include <hip/hip_runtime.h>

#define NROWS 8192
#define BBND  32
#define CBND  512
#define JQ    4096            // j-range per block (2 halves)
#define NR    64              // rounds of 64j per block
#define ABUFB 8192            // A LDS buffer bytes (64 rows x 128B)

typedef unsigned short u16;
typedef unsigned int   u32;
typedef __bf16 bf16x8 __attribute__((ext_vector_type(8)));
typedef float  f32x4  __attribute__((ext_vector_type(4)));
typedef float  f32x16 __attribute__((ext_vector_type(16)));
typedef u32    u32x4  __attribute__((ext_vector_type(4)));
typedef u32    u32x2  __attribute__((ext_vector_type(2)));

#define ZERO4  (f32x4){0.f,0.f,0.f,0.f}
#define ZERO16 (f32x16){0.f,0.f,0.f,0.f,0.f,0.f,0.f,0.f,0.f,0.f,0.f,0.f,0.f,0.f,0.f,0.f}

// raw barrier: drain LDS ops, keep global loads in flight (no vmcnt drain)
#define BAR asm volatile("s_waitcnt lgkmcnt(0)\n\ts_barrier" ::: "memory")

static __device__ inline u16 f2bf(float f) {
    unsigned u = __builtin_bit_cast(unsigned, f);
    unsigned r = (u + 0x7FFFu + ((u >> 16) & 1u)) >> 16;
    return (u16)r;
}

static __device__ inline float pow14(float base) {
    return __builtin_amdgcn_exp2f(1.4f * __builtin_amdgcn_logf(base));
}

static __device__ inline float adj_eval(float dot, float sij) {
    float x = fabsf(2.f * dot - sij);
    float base = fmaxf(1.f - x * (1.f / 32.f), 0.f);
    return pow14(base);
}

static __device__ inline float sigmoidf_fast(float v) {
    float e = __builtin_amdgcn_exp2f(-1.44269504f * v);
    return 1.f / (1.f + e);
}

static __device__ inline u32 cvtpk(float a, float b) {
    u32 r;
    asm("v_cvt_pk_bf16_f32 %0, %1, %2" : "=v"(r) : "v"(a), "v"(b));
    return r;
}

static __device__ inline f32x4 MFMA16(bf16x8 a, bf16x8 b, f32x4 c) {
    return __builtin_amdgcn_mfma_f32_16x16x32_bf16(a, b, c, 0, 0, 0);
}
static __device__ inline f32x16 MFMA32(bf16x8 a, bf16x8 b, f32x16 c) {
    return __builtin_amdgcn_mfma_f32_32x32x16_bf16(a, b, c, 0, 0, 0);
}

// ---------------- prep: row sums of bbn + bf16 copy ----------------
__global__ __launch_bounds__(256) void k_prep_rows(const float* __restrict__ bbn,
                                                   float* __restrict__ s,
                                                   u16* __restrict__ bbn_bf) {
    int i = blockIdx.x * 256 + threadIdx.x;
    if (i >= NROWS) return;
    const f32x4* row = reinterpret_cast<const f32x4*>(bbn + i * BBND);
    float sum = 0.f;
    u16* dst = bbn_bf + i * BBND;
#pragma unroll
    for (int q = 0; q < 8; ++q) {
        f32x4 v = row[q];
#pragma unroll
        for (int e = 0; e < 4; ++e) {
            sum += v[e];
            dst[q * 4 + e] = f2bf(v[e]);
        }
    }
    s[i] = sum;
}

// ---------------- prep: W transpose -> bf16 ----------------
__global__ __launch_bounds__(256) void k_prep_wt(const float* __restrict__ W,
                                                 u16* __restrict__ WT) {
    int idx = blockIdx.x * 256 + threadIdx.x;   // over 512*512
    int c = idx >> 9, k = idx & 511;
    WT[idx] = f2bf(W[k * CBND + c]);            // WT[c][k]
}

// ---------------- degree: d_i = sum_j adj_ij ; dinv = rsqrt(d+eps) ----------------
__global__ __launch_bounds__(512) void k_deg(const u16* __restrict__ bbn_bf,
                                             const float* __restrict__ s,
                                             float* __restrict__ dinv) {
    __shared__ float part[8][16];
    int ibase = blockIdx.x * 16;
    int tid = threadIdx.x;
    int w = tid >> 6, l = tid & 63, lg = l >> 4, lr = l & 15;

    bf16x8 afrag = *reinterpret_cast<const bf16x8*>(bbn_bf + (ibase + lr) * BBND + lg * 8);
    float si[4];
#pragma unroll
    for (int r = 0; r < 4; ++r) si[r] = s[ibase + lg * 4 + r];

    float dacc[4] = {0.f, 0.f, 0.f, 0.f};
    int j0 = w * (NROWS / 8);
    for (int jt = 0; jt < NROWS / 8; jt += 16) {
        int jb = j0 + jt;
        bf16x8 bfrag = *reinterpret_cast<const bf16x8*>(bbn_bf + (jb + lr) * BBND + lg * 8);
        f32x4 dot = MFMA16(afrag, bfrag, ZERO4);
        float sj = s[jb + lr];
#pragma unroll
        for (int r = 0; r < 4; ++r) dacc[r] += adj_eval(dot[r], si[r] + sj);
    }
#pragma unroll
    for (int off = 1; off < 16; off <<= 1)
#pragma unroll
        for (int r = 0; r < 4; ++r) dacc[r] += __shfl_xor(dacc[r], off, 64);

    if (lr == 0) {
#pragma unroll
        for (int r = 0; r < 4; ++r) part[w][lg * 4 + r] = dacc[r];
    }
    __syncthreads();
    if (tid < 16) {
        float d = 0.f;
#pragma unroll
        for (int q = 0; q < 8; ++q) d += part[q][tid];
        dinv[ibase + tid] = rsqrtf(d + 1e-8f);
    }
}

// ---------------- fc: g_blk[(j>>3)*512 + c][j&7] = dinv_j * (cbn@W + b)[j][c] ----------------
// LDS-staged (round-14, proven): one block per 64-j tile, cbn tile bf16 in LDS
// once, consumed by all 8 c-quadrants -> cbn read from HBM exactly once.
__global__ __launch_bounds__(512) void k_fc(const float* __restrict__ cbn,
                                            const u16* __restrict__ WT,
                                            const float* __restrict__ bvec,
                                            const float* __restrict__ dinv,
                                            u16* __restrict__ g_blk) {
    __shared__ __align__(16) u16 Clds[64 * 512];   // 64 j-rows x 512 k (bf16)
    int jcol = blockIdx.x * 64;
    int tid = threadIdx.x;
    int w = tid >> 6, l = tid & 63, lg = l >> 4, lr = l & 15;
    int wq = w & 3, jh = w >> 2;

    char* Cl = (char*)&Clds[0];

#pragma unroll
    for (int p = 0; p < 8; ++p) {
        int gidx = p * 512 + tid;
        int row = gidx >> 6, sl = gidx & 63;
        const f32x4* src = reinterpret_cast<const f32x4*>(cbn + (jcol + row) * CBND + sl * 8);
        f32x4 v0 = src[0], v1 = src[1];
        bf16x8 bv;
#pragma unroll
        for (int e = 0; e < 4; ++e) { bv[e] = (__bf16)v0[e]; bv[e + 4] = (__bf16)v1[e]; }
        *reinterpret_cast<bf16x8*>(Cl + row * 1024 + ((sl ^ (row & 7)) << 4)) = bv;
    }
    __syncthreads();

    int r7 = lr & 7;
    for (int cb = 0; cb < 8; ++cb) {
        int crow = cb * 64 + wq * 16;
        f32x4 acc0 = ZERO4, acc1 = ZERO4;
        for (int k0 = 0; k0 < CBND; k0 += 32) {
            bf16x8 afrag = *reinterpret_cast<const bf16x8*>(WT + (crow + lr) * CBND + k0 + lg * 8);
            int slot = (k0 >> 3) + lg;
            int row0 = jh * 32 + lr;
            bf16x8 b0 = *reinterpret_cast<const bf16x8*>(Cl + row0 * 1024 + ((slot ^ r7) << 4));
            bf16x8 b1 = *reinterpret_cast<const bf16x8*>(Cl + (row0 + 16) * 1024 + ((slot ^ r7) << 4));
            acc0 = MFMA16(afrag, b0, acc0);
            acc1 = MFMA16(afrag, b1, acc1);
        }
#pragma unroll
        for (int f = 0; f < 2; ++f) {
            f32x4 af = f ? acc1 : acc0;
#pragma unroll
            for (int r = 0; r < 4; ++r) {
                int c = crow + lg * 4 + r;
                int j = jcol + jh * 32 + f * 16 + lr;
                float val = af[r] + bvec[c];
                g_blk[(((j >> 3) * 512 + c) << 3) + (j & 7)] = f2bf(val * dinv[j]);
            }
        }
    }
}

// ---------------- conv: partial sums P[jh] = sum_{j in half} adj_ij * g[:,j] ----------------
// Round-11 structure, ONE change: wave acc tile 64i x 32c (was 32i x 64c).
// 16 waves x 32c = 512c with NO iw duplication -> every B element loaded
// exactly once (L2 B traffic 2.1 -> 1.05 GB). Per wave per st: 8 MFMA32
// (2 i-frags x 4 k-steps), A-LDS reads 8 b128 (was 4), B 4 b128 (was 4, dup'd).
// Regs: 32 AGPR acc + 2x16 VGPR staging ~ 95 total, safe under (1024,4)'s 128.
// Gen, A-layout/swizzle, per-element j-ascending MFMA chain: r11-VERBATIM ->
// sums bit-identical (absmax 0.00390625).

#define LOADB(T, R) { \
    const char* p = gB + (long)(T) * 65536; \
    R##0 = *reinterpret_cast<const u32x4*>(p); \
    R##1 = *reinterpret_cast<const u32x4*>(p + 16384); \
    R##2 = *reinterpret_cast<const u32x4*>(p + 32768); \
    R##3 = *reinterpret_cast<const u32x4*>(p + 49152); \
}

#define GEN(ST, WB) { \
    int jg = jbase + (ST) * 64 + jq8 * 16; \
    bf16x8 fJ = *reinterpret_cast<const bf16x8*>(bbn_bf + (jg + lr) * BBND + lg * 8); \
    f32x4 sj = *reinterpret_cast<const f32x4*>(s + jg + lg * 4); \
    f32x4 dot = MFMA16(fJ, fragI, ZERO4); \
    u32 p0 = cvtpk(adj_eval(dot[0], si + sj[0]), adj_eval(dot[1], si + sj[1])); \
    u32 p1 = cvtpk(adj_eval(dot[2], si + sj[2]), adj_eval(dot[3], si + sj[3])); \
    *reinterpret_cast<u32x2*>(Ab + (WB) * ABUFB + gw) = (u32x2){p0, p1}; \
}

#define CONVP(RB, R) { \
    const char* Ar = Ab + (RB) * ABUFB; \
    bf16x8 t0l = *reinterpret_cast<const bf16x8*>(Ar + a0); \
    bf16x8 t0h = *reinterpret_cast<const bf16x8*>(Ar + a0 + 4096); \
    c00 = MFMA32(t0l, __builtin_bit_cast(bf16x8, R##0), c00); \
    c10 = MFMA32(t0h, __builtin_bit_cast(bf16x8, R##0), c10); \
    bf16x8 t1l = *reinterpret_cast<const bf16x8*>(Ar + a1); \
    bf16x8 t1h = *reinterpret_cast<const bf16x8*>(Ar + a1 + 4096); \
    c00 = MFMA32(t1l, __builtin_bit_cast(bf16x8, R##1), c00); \
    c10 = MFMA32(t1h, __builtin_bit_cast(bf16x8, R##1), c10); \
    bf16x8 t2l = *reinterpret_cast<const bf16x8*>(Ar + a2); \
    bf16x8 t2h = *reinterpret_cast<const bf16x8*>(Ar + a2 + 4096); \
    c00 = MFMA32(t2l, __builtin_bit_cast(bf16x8, R##2), c00); \
    c10 = MFMA32(t2h, __builtin_bit_cast(bf16x8, R##2), c10); \
    bf16x8 t3l = *reinterpret_cast<const bf16x8*>(Ar + a3); \
    bf16x8 t3h = *reinterpret_cast<const bf16x8*>(Ar + a3 + 4096); \
    c00 = MFMA32(t3l, __builtin_bit_cast(bf16x8, R##3), c00); \
    c10 = MFMA32(t3h, __builtin_bit_cast(bf16x8, R##3), c10); \
}

#define EPI(ACC, IH) { \
    _Pragma("unroll") \
    for (int reg = 0; reg < 16; ++reg) { \
        int rowD = (reg & 3) + 8 * (reg >> 2) + 4 * lh; \
        Pq[(long)(ibase + (IH) * 32 + rowD) * CBND + w * 32 + l31] = ACC[reg]; \
    } \
}

__global__ __launch_bounds__(1024, 4) void k_conv(const u16* __restrict__ bbn_bf,
                                                  const float* __restrict__ s,
                                                  const u16* __restrict__ g_blk,
                                                  float* __restrict__ P) {
    __shared__ __align__(16) u16 Alds[2][64 * 64];   // 2 x 8KB supertiles

    int bx = blockIdx.x;
    int jq = bx & 1;                   // j-half; constant per XCD (stride-8 dispatch)
    int it = bx >> 1;                  // 0..127
    int ibase = it * 64;
    int jbase = jq * JQ;

    int tid = threadIdx.x;
    int w = tid >> 6, l = tid & 63;
    int lr = l & 15, lg = l >> 4, l31 = l & 31, lh = l >> 5;
    int iq = w & 3, jq8 = w >> 2;      // gen wave tile: 16i x 16j (4x4 waves)

    // gen hoists
    bf16x8 fragI = *reinterpret_cast<const bf16x8*>(bbn_bf + (ibase + iq * 16 + lr) * BBND + lg * 8);
    float si = s[ibase + iq * 16 + lr];

    char* Ab = (char*)&Alds[0][0];
    float* Pq = P + (long)jq * (NROWS * CBND);

    // B global base: octet (jbase/8 + T*8 + t*2 + lh), c = w*32 + l31
    const char* gB = (const char*)g_blk + (long)jbase * 1024 + lh * 8192
                   + (w * 32 + l31) * 16;

    // A-frag reads: rows l31 (i-lo) / l31+32 (i-hi, +4096B), k-step t slot = 2t+lh,
    // phys = slot ^ (row&7); (l31+32)&7 == l31&7 so i-hi shares the XOR.
    int r7 = l31 & 7;
    int abase = l31 * 128;
    int a0 = abase + (((0 + lh) ^ r7) << 4);
    int a1 = abase + (((2 + lh) ^ r7) << 4);
    int a2 = abase + (((4 + lh) ^ r7) << 4);
    int a3 = abase + (((6 + lh) ^ r7) << 4);

    // gen write: row = iq*16+lr, logical slot = jq8*2 + (lg>>1), byte +(lg&1)*8
    int grow = iq * 16 + lr;
    int gw = grow * 128 + (((jq8 * 2 + (lg >> 1)) ^ (grow & 7)) << 4) + (lg & 1) * 8;

    f32x16 c00 = ZERO16, c10 = ZERO16;

    u32x4 rA0, rA1, rA2, rA3;
    u32x4 rB0, rB1, rB2, rB3;

    // prologue: supertile 0 into buf0, B(st=0) into rA
    GEN(0, 0);
    LOADB(0, rA);
    BAR;

    for (int st2 = 0; st2 < NR; st2 += 2) {
        LOADB(st2 + 1, rB);
        GEN(st2 + 1, 1);
        CONVP(0, rA);
        BAR;
        int tn = (st2 + 2 < NR) ? st2 + 2 : NR - 1;   // tail: redundant, never read
        LOADB(tn, rA);
        GEN(tn, 0);
        CONVP(1, rB);
        BAR;
    }

    EPI(c00, 0);
    EPI(c10, 1);
}

// ---------------- combine: out = sigmoid(dinv_i * (P0 + P1)) ----------------
__global__ __launch_bounds__(256) void k_comb(const float* __restrict__ dinv,
                                              const float* __restrict__ P,
                                              float* __restrict__ out) {
    int idx = blockIdx.x * 256 + threadIdx.x;   // f32x4 index; 1,048,576 total
    float di = dinv[idx >> 7];
    f32x4 a = *reinterpret_cast<const f32x4*>(P + (long)idx * 4);
    f32x4 b = *reinterpret_cast<const f32x4*>(P + (long)NROWS * CBND + (long)idx * 4);
    f32x4 v;
#pragma unroll
    for (int e = 0; e < 4; ++e) v[e] = sigmoidf_fast((a[e] + b[e]) * di);
    *reinterpret_cast<f32x4*>(out + (long)idx * 4) = v;
}

extern "C" void kernel_launch(void* const* d_in, const int* in_sizes, int n_in,
                              void* d_out, int out_size, void* d_ws, size_t ws_size,
                              hipStream_t stream) {
    const float* bbn = (const float*)d_in[0];   // [8192,32]
    const float* cbn = (const float*)d_in[1];   // [8192,512]
    const float* W   = (const float*)d_in[2];   // [512,512]
    const float* b   = (const float*)d_in[3];   // [512]
    float* out = (float*)d_out;                 // [8192,512] f32

    char* ws = (char*)d_ws;
    float* s      = (float*)ws;  ws += NROWS * 4;
    float* dinv   = (float*)ws;  ws += NROWS * 4;
    u16* bbn_bf   = (u16*)ws;    ws += NROWS * BBND * 2;
    u16* WT       = (u16*)ws;    ws += CBND * CBND * 2;
    u16* g_blk    = (u16*)ws;    ws += (size_t)CBND * NROWS * 2;
    float* P      = (float*)ws;  ws += (size_t)2 * NROWS * CBND * 4;   // 32MB partials

    k_prep_rows<<<NROWS / 256, 256, 0, stream>>>(bbn, s, bbn_bf);
    k_prep_wt<<<(CBND * CBND) / 256, 256, 0, stream>>>(W, WT);
    k_deg<<<NROWS / 16, 512, 0, stream>>>(bbn_bf, s, dinv);
    k_fc<<<NROWS / 64, 512, 0, stream>>>(cbn, WT, b, dinv, g_blk);
    k_conv<<<(NROWS / 64) * 2, 1024, 0, stream>>>(bbn_bf, s, g_blk, P);
    k_comb<<<(NROWS * CBND / 4) / 256, 256, 0, stream>>>(dinv, P, out);
}